// Round 6
// baseline (215.399 us; speedup 1.0000x reference)
//
#include <hip/hip_runtime.h>
#include <stdint.h>

#define NCH   30                   // channels per cell (cell = 120 B)
#define TPB   128                  // 2 waves per block
#define TILE  128                  // cells per tile (one per thread)
#define TW    (TILE * NCH)         // 3840 floats per array per tile
#define TF4   (TW / 4)             // 960 float4 chunks per array per tile
#define NBLK  1280                 // 5 blocks/CU (LDS 30.7 KB) * 256 CUs

__device__ __forceinline__ float iou_f(float x1, float y1, float w1, float h1,
                                       float x2, float y2, float w2, float h2) {
    float l1 = x1 - 0.5f * w1, r1 = x1 + 0.5f * w1;
    float t1 = y1 - 0.5f * h1, b1 = y1 + 0.5f * h1;
    float l2 = x2 - 0.5f * w2, r2 = x2 + 0.5f * w2;
    float t2 = y2 - 0.5f * h2, b2 = y2 + 0.5f * h2;
    float in_h = fminf(b1, b2) - fmaxf(t1, t2);
    float in_w = fminf(r1, r2) - fmaxf(l1, l2);
    float inter = (in_h < 0.f || in_w < 0.f) ? 0.f : in_h * in_w;
    float a1 = (b1 - t1) * (r1 - l1);
    float a2 = (b2 - t2) * (r2 - l2);
    return inter / (a1 + a2 - inter);
}

// Compute the 5 loss terms for the cell at pp/lp (LDS or global), accumulate.
// Masked-out lanes return before touching pp (whose chunks may be un-staged).
__device__ __forceinline__ void cell_loss(const float* __restrict__ pp,
                                          const float* __restrict__ lp,
                                          float& v0, float& v1, float& v2,
                                          float& v3, float& v4) {
    const float2 l01 = *(const float2*)(lp);        // mask, gx
    const float mask = l01.x;
    if (mask == 0.f) return;

    const float2 l23 = *(const float2*)(lp + 2);    // gy, gw
    const float2 l45 = *(const float2*)(lp + 4);    // gh, -
    const float gx = l01.y, gy = l23.x, gw = l23.y, gh = l45.x;

    const float2 p01 = *(const float2*)(pp);        // -, b1x
    const float2 p23 = *(const float2*)(pp + 2);    // b1y, b1w
    const float2 p45 = *(const float2*)(pp + 4);    // b1h, -
    const float2 p67 = *(const float2*)(pp + 6);    // b2x, b2y
    const float2 p89 = *(const float2*)(pp + 8);    // b2w, b2h

    const float i1 = iou_f(p01.y, p23.x, p23.y, p45.x, gx, gy, gw, gh);
    const float i2 = iou_f(p67.x, p67.y, p89.x, p89.y, gx, gy, gw, gh);
    const bool best = (i1 >= i2);
    const float sx = best ? p01.y : p67.x;
    const float sy = best ? p23.x : p67.y;
    const float sw = best ? p23.y : p89.x;
    const float sh = best ? p45.x : p89.y;
    const float imax = best ? i1 : i2;
    const float imin = best ? i2 : i1;

    const float center = 5.f * ((sx - gx) * (sx - gx) + (sy - gy) * (sy - gy));
    const float dw = sqrtf(sw) - sqrtf(gw);
    const float dh = sqrtf(sh) - sqrtf(gh);
    const float wh = 5.f * (dw * dw + dh * dh);

    float cls = 0.f;
#pragma unroll
    for (int k = 0; k < 10; ++k) {                  // channels 10..29
        const float2 pd = *(const float2*)(pp + 10 + 2 * k);
        const float2 ld = *(const float2*)(lp + 10 + 2 * k);
        const float dx = pd.x - ld.x;
        const float dy = pd.y - ld.y;
        cls += dx * dx + dy * dy;
    }

    v0 += center * mask;
    v1 += wh * mask;
    v2 += imax * mask;
    v3 += imin * mask;
    v4 += cls * mask;
}

// Persistent 2-wave blocks, 5/CU. Per 128-cell tile:
//   1) stage labels tile unconditionally (coalesced float4 -> LDS)
//   2) ballot per-wave mask bits -> LDS bitmap
//   3) stage pred tile PREDICATED per float4 chunk: skip chunks whose covering
//      cells are all masked-out (~58% of pred lines never fetched, p=0.3)
//   4) per-thread cell_loss from LDS (masked-out lanes exit early)
__global__ __launch_bounds__(TPB) void yolo_partial(const float* __restrict__ pred,
                                                    const float* __restrict__ lab,
                                                    float* __restrict__ partial,
                                                    int n_cells) {
    __shared__ float sl[TW];                 // labels tile (15,360 B)
    __shared__ float sp[TW];                 // pred tile   (15,360 B)
    __shared__ unsigned long long sbits[TPB / 64];
    __shared__ float red[5][TPB / 64];

    const int tid  = threadIdx.x;
    const int wave = tid >> 6;
    const int lane = tid & 63;
    const int bid  = blockIdx.x;
    const int NB   = gridDim.x;
    const int nt   = n_cells / TILE;         // 6272 full tiles

    float v0 = 0.f, v1 = 0.f, v2 = 0.f, v3 = 0.f, v4 = 0.f;

    for (int t = bid; t < nt; t += NB) {
        const size_t base = (size_t)t * TW;

        // ---- 1) stage labels (960 float4 over 128 threads) ----
#pragma unroll
        for (int i = 0; i < 8; ++i) {
            const int idx = i * TPB + tid;          // [0, 1024)
            if (idx < TF4)
                *(float4*)(sl + (size_t)idx * 4) =
                    *(const float4*)(lab + base + (size_t)idx * 4);
        }
        __syncthreads();

        // ---- 2) mask bitmap (cell tid -> bit lane of wave) ----
        const float my_mask = sl[tid * NCH];
        const unsigned long long bits = __ballot(my_mask != 0.f);
        if (lane == 0) sbits[wave] = bits;
        __syncthreads();

        const unsigned long long b0 = sbits[0];
        const unsigned long long b1 = sbits[1];

        // ---- 3) stage pred, predicated per chunk ----
#pragma unroll
        for (int i = 0; i < 8; ++i) {
            const int idx = i * TPB + tid;
            if (idx < TF4) {
                const int f0 = idx * 4;             // first float of chunk
                const int c0 = f0 / NCH;            // covering cells (magic-mul)
                const int c1 = (f0 + 3) / NCH;
                const bool n0 = (c0 < 64) ? ((b0 >> c0) & 1ull) : ((b1 >> (c0 - 64)) & 1ull);
                const bool n1 = (c1 < 64) ? ((b0 >> c1) & 1ull) : ((b1 >> (c1 - 64)) & 1ull);
                if (n0 || n1)
                    *(float4*)(sp + (size_t)idx * 4) =
                        *(const float4*)(pred + base + (size_t)idx * 4);
            }
        }
        __syncthreads();

        // ---- 4) compute: one cell per thread ----
        cell_loss(sp + tid * NCH, sl + tid * NCH, v0, v1, v2, v3, v4);
        __syncthreads();   // protect sl/sp before next tile's staging
    }

    // Remainder cells — direct from global (never taken: 802816 % 128 == 0).
    const int rem_start = nt * TILE;
    if (bid == 0 && rem_start < n_cells) {
        for (int c = rem_start + tid; c < n_cells; c += TPB) {
            cell_loss(pred + (size_t)c * NCH, lab + (size_t)c * NCH,
                      v0, v1, v2, v3, v4);
        }
    }

    // ---- block reduction: 2 waves ----
#pragma unroll
    for (int off = 32; off > 0; off >>= 1) {
        v0 += __shfl_down(v0, off);
        v1 += __shfl_down(v1, off);
        v2 += __shfl_down(v2, off);
        v3 += __shfl_down(v3, off);
        v4 += __shfl_down(v4, off);
    }
    if (lane == 0) {
        red[0][wave] = v0;
        red[1][wave] = v1;
        red[2][wave] = v2;
        red[3][wave] = v3;
        red[4][wave] = v4;
    }
    __syncthreads();
    if (tid < 5) {
        float sacc = 0.f;
#pragma unroll
        for (int w = 0; w < TPB / 64; ++w) sacc += red[tid][w];
        partial[(size_t)bid * 5 + tid] = sacc;
    }
}

// Reduce n_blocks x 5 partials -> out[0..4]. One block.
__global__ __launch_bounds__(256) void final_reduce(const float* __restrict__ partial,
                                                    float* __restrict__ out,
                                                    int n_blocks) {
    __shared__ float red[5][4];
    const int tid = threadIdx.x;
    float v0 = 0.f, v1 = 0.f, v2 = 0.f, v3 = 0.f, v4 = 0.f;
    for (int b = tid; b < n_blocks; b += 256) {
        const float* p = partial + (size_t)b * 5;
        v0 += p[0]; v1 += p[1]; v2 += p[2]; v3 += p[3]; v4 += p[4];
    }
#pragma unroll
    for (int off = 32; off > 0; off >>= 1) {
        v0 += __shfl_down(v0, off);
        v1 += __shfl_down(v1, off);
        v2 += __shfl_down(v2, off);
        v3 += __shfl_down(v3, off);
        v4 += __shfl_down(v4, off);
    }
    const int wave = tid >> 6;
    const int lane = tid & 63;
    if (lane == 0) {
        red[0][wave] = v0;
        red[1][wave] = v1;
        red[2][wave] = v2;
        red[3][wave] = v3;
        red[4][wave] = v4;
    }
    __syncthreads();
    if (tid < 5) {
        float sacc = 0.f;
#pragma unroll
        for (int w = 0; w < 4; ++w) sacc += red[tid][w];
        out[tid] = sacc;
    }
}

extern "C" void kernel_launch(void* const* d_in, const int* in_sizes, int n_in,
                              void* d_out, int out_size, void* d_ws, size_t ws_size,
                              hipStream_t stream) {
    const float* pred = (const float*)d_in[0];
    const float* lab  = (const float*)d_in[1];
    float* out = (float*)d_out;
    float* partial = (float*)d_ws;                 // 1280*5*4 = 25,600 B

    const int n_cells = in_sizes[0] / NCH;         // 802816

    hipLaunchKernelGGL(yolo_partial, dim3(NBLK), dim3(TPB), 0, stream,
                       pred, lab, partial, n_cells);
    hipLaunchKernelGGL(final_reduce, dim3(1), dim3(256), 0, stream,
                       partial, out, NBLK);
}

// Round 7
// 210.809 us; speedup vs baseline: 1.0218x; 1.0218x over previous
//
#include <hip/hip_runtime.h>
#include <stdint.h>

#define NCH   30                   // channels per cell (cell = 120 B)
#define TPB   256                  // 4 waves per block
#define TILE  64                   // cells per tile
#define TW    (TILE * NCH)         // 1920 floats per array per tile
#define TF4   (TW / 4)             // 480 float4 chunks per array per tile
#define NBLK  2048                 // 8 blocks/CU * 256 CUs (LDS 15.4KB -> 100% occ)

__device__ __forceinline__ float iou_f(float x1, float y1, float w1, float h1,
                                       float x2, float y2, float w2, float h2) {
    float l1 = x1 - 0.5f * w1, r1 = x1 + 0.5f * w1;
    float t1 = y1 - 0.5f * h1, b1 = y1 + 0.5f * h1;
    float l2 = x2 - 0.5f * w2, r2 = x2 + 0.5f * w2;
    float t2 = y2 - 0.5f * h2, b2 = y2 + 0.5f * h2;
    float in_h = fminf(b1, b2) - fmaxf(t1, t2);
    float in_w = fminf(r1, r2) - fmaxf(l1, l2);
    float inter = (in_h < 0.f || in_w < 0.f) ? 0.f : in_h * in_w;
    float a1 = (b1 - t1) * (r1 - l1);
    float a2 = (b2 - t2) * (r2 - l2);
    return inter / (a1 + a2 - inter);
}

// Compute the 5 loss terms for the cell at pp/lp (LDS or global), accumulate.
__device__ __forceinline__ void cell_loss(const float* __restrict__ pp,
                                          const float* __restrict__ lp,
                                          float& v0, float& v1, float& v2,
                                          float& v3, float& v4) {
    const float2 l01 = *(const float2*)(lp);        // mask, gx
    const float mask = l01.x;
    if (mask == 0.f) return;

    const float2 l23 = *(const float2*)(lp + 2);    // gy, gw
    const float2 l45 = *(const float2*)(lp + 4);    // gh, -
    const float gx = l01.y, gy = l23.x, gw = l23.y, gh = l45.x;

    const float2 p01 = *(const float2*)(pp);        // -, b1x
    const float2 p23 = *(const float2*)(pp + 2);    // b1y, b1w
    const float2 p45 = *(const float2*)(pp + 4);    // b1h, -
    const float2 p67 = *(const float2*)(pp + 6);    // b2x, b2y
    const float2 p89 = *(const float2*)(pp + 8);    // b2w, b2h

    const float i1 = iou_f(p01.y, p23.x, p23.y, p45.x, gx, gy, gw, gh);
    const float i2 = iou_f(p67.x, p67.y, p89.x, p89.y, gx, gy, gw, gh);
    const bool best = (i1 >= i2);
    const float sx = best ? p01.y : p67.x;
    const float sy = best ? p23.x : p67.y;
    const float sw = best ? p23.y : p89.x;
    const float sh = best ? p45.x : p89.y;
    const float imax = best ? i1 : i2;
    const float imin = best ? i2 : i1;

    const float center = 5.f * ((sx - gx) * (sx - gx) + (sy - gy) * (sy - gy));
    const float dw = sqrtf(sw) - sqrtf(gw);
    const float dh = sqrtf(sh) - sqrtf(gh);
    const float wh = 5.f * (dw * dw + dh * dh);

    float cls = 0.f;
#pragma unroll
    for (int k = 0; k < 10; ++k) {                  // channels 10..29
        const float2 pd = *(const float2*)(pp + 10 + 2 * k);
        const float2 ld = *(const float2*)(lp + 10 + 2 * k);
        const float dx = pd.x - ld.x;
        const float dy = pd.y - ld.y;
        cls += dx * dx + dy * dy;
    }

    v0 += center * mask;
    v1 += wh * mask;
    v2 += imax * mask;
    v3 += imin * mask;
    v4 += cls * mask;
}

// Max-occupancy staging: 64-cell tiles (15.4 KB LDS) staged by 256-thread
// blocks -> 8 blocks/CU = 32 waves/CU (100% occupancy). Per tile each thread
// issues at most 4 float4 loads (short-lived regs -> ds_write). Wave 0
// computes the 64 cells; memory latency is hidden by 8 independent block
// pipelines per CU (4x the TLP of all prior rounds).
__global__ __launch_bounds__(TPB) void yolo_partial(const float* __restrict__ pred,
                                                    const float* __restrict__ lab,
                                                    float* __restrict__ partial,
                                                    int n_cells) {
    __shared__ float s[2 * TW];              // pred tile [0,1920), lab tile [1920,3840)
    __shared__ float red[5][TPB / 64];

    const int tid  = threadIdx.x;
    const int wave = tid >> 6;
    const int lane = tid & 63;
    const int bid  = blockIdx.x;
    const int NB   = gridDim.x;
    const int nt   = n_cells / TILE;         // 12544 full tiles

    float v0 = 0.f, v1 = 0.f, v2 = 0.f, v3 = 0.f, v4 = 0.f;

    // combined float4 index space: [0,480) = pred chunks, [480,960) = lab chunks
    const int i0 = tid, i1 = tid + TPB, i2 = tid + 2 * TPB, i3 = tid + 3 * TPB;

    for (int t = bid; t < nt; t += NB) {
        const size_t gbase = (size_t)t * TW;

        // ---- stage: up to 4 loads/thread, immediately spilled to LDS ----
        {
            const float4* s0 = (const float4*)((i0 < TF4 ? pred + gbase + (size_t)i0 * 4
                                                         : lab  + gbase + (size_t)(i0 - TF4) * 4));
            const float4* s1 = (const float4*)((i1 < TF4 ? pred + gbase + (size_t)i1 * 4
                                                         : lab  + gbase + (size_t)(i1 - TF4) * 4));
            const float4* s2 = (const float4*)((i2 < TF4 ? pred + gbase + (size_t)i2 * 4
                                                         : lab  + gbase + (size_t)(i2 - TF4) * 4));
            float4 r0 = *s0;
            float4 r1 = *s1;
            float4 r2 = *s2;
            float4 r3;
            if (i3 < 2 * TF4) {
                const float4* s3 = (const float4*)((i3 < TF4 ? pred + gbase + (size_t)i3 * 4
                                                             : lab  + gbase + (size_t)(i3 - TF4) * 4));
                r3 = *s3;
            }
            *(float4*)(s + (size_t)i0 * 4) = r0;
            *(float4*)(s + (size_t)i1 * 4) = r1;
            *(float4*)(s + (size_t)i2 * 4) = r2;
            if (i3 < 2 * TF4) *(float4*)(s + (size_t)i3 * 4) = r3;
        }
        __syncthreads();

        // ---- compute: wave 0 handles the 64 cells (one per lane) ----
        if (tid < TILE) {
            cell_loss(s + tid * NCH, s + TW + tid * NCH, v0, v1, v2, v3, v4);
        }
        __syncthreads();   // protect s before next tile's staging
    }

    // Remainder cells — direct from global (never taken: 802816 % 64 == 0).
    const int rem_start = nt * TILE;
    if (bid == 0 && rem_start < n_cells) {
        for (int c = rem_start + tid; c < n_cells; c += TPB) {
            cell_loss(pred + (size_t)c * NCH, lab + (size_t)c * NCH,
                      v0, v1, v2, v3, v4);
        }
    }

    // ---- block reduction (only wave 0 carries nonzero, kept generic) ----
#pragma unroll
    for (int off = 32; off > 0; off >>= 1) {
        v0 += __shfl_down(v0, off);
        v1 += __shfl_down(v1, off);
        v2 += __shfl_down(v2, off);
        v3 += __shfl_down(v3, off);
        v4 += __shfl_down(v4, off);
    }
    if (lane == 0) {
        red[0][wave] = v0;
        red[1][wave] = v1;
        red[2][wave] = v2;
        red[3][wave] = v3;
        red[4][wave] = v4;
    }
    __syncthreads();
    if (tid < 5) {
        float sacc = 0.f;
#pragma unroll
        for (int w = 0; w < TPB / 64; ++w) sacc += red[tid][w];
        partial[(size_t)bid * 5 + tid] = sacc;
    }
}

// Reduce n_blocks x 5 partials -> out[0..4]. One block.
__global__ __launch_bounds__(256) void final_reduce(const float* __restrict__ partial,
                                                    float* __restrict__ out,
                                                    int n_blocks) {
    __shared__ float red[5][4];
    const int tid = threadIdx.x;
    float v0 = 0.f, v1 = 0.f, v2 = 0.f, v3 = 0.f, v4 = 0.f;
    for (int b = tid; b < n_blocks; b += 256) {
        const float* p = partial + (size_t)b * 5;
        v0 += p[0]; v1 += p[1]; v2 += p[2]; v3 += p[3]; v4 += p[4];
    }
#pragma unroll
    for (int off = 32; off > 0; off >>= 1) {
        v0 += __shfl_down(v0, off);
        v1 += __shfl_down(v1, off);
        v2 += __shfl_down(v2, off);
        v3 += __shfl_down(v3, off);
        v4 += __shfl_down(v4, off);
    }
    const int wave = tid >> 6;
    const int lane = tid & 63;
    if (lane == 0) {
        red[0][wave] = v0;
        red[1][wave] = v1;
        red[2][wave] = v2;
        red[3][wave] = v3;
        red[4][wave] = v4;
    }
    __syncthreads();
    if (tid < 5) {
        float sacc = 0.f;
#pragma unroll
        for (int w = 0; w < 4; ++w) sacc += red[tid][w];
        out[tid] = sacc;
    }
}

extern "C" void kernel_launch(void* const* d_in, const int* in_sizes, int n_in,
                              void* d_out, int out_size, void* d_ws, size_t ws_size,
                              hipStream_t stream) {
    const float* pred = (const float*)d_in[0];
    const float* lab  = (const float*)d_in[1];
    float* out = (float*)d_out;
    float* partial = (float*)d_ws;                 // 2048*5*4 = 40,960 B

    const int n_cells = in_sizes[0] / NCH;         // 802816

    hipLaunchKernelGGL(yolo_partial, dim3(NBLK), dim3(TPB), 0, stream,
                       pred, lab, partial, n_cells);
    hipLaunchKernelGGL(final_reduce, dim3(1), dim3(256), 0, stream,
                       partial, out, NBLK);
}

// Round 8
// 200.864 us; speedup vs baseline: 1.0724x; 1.0495x over previous
//
#include <hip/hip_runtime.h>
#include <stdint.h>

#define NCH   30                   // channels per cell (cell = 120 B)
#define TPB   256                  // 4 waves per block
#define TILE  64                   // cells per tile
#define TW    (TILE * NCH)         // 1920 floats per array per tile
#define TF4   (TW / 4)             // 480 float4 chunks per array per tile
#define NBLK  1536                 // 6 blocks/CU (23.2 KB LDS) * 256 CUs

__device__ __forceinline__ float iou_f(float x1, float y1, float w1, float h1,
                                       float x2, float y2, float w2, float h2) {
    float l1 = x1 - 0.5f * w1, r1 = x1 + 0.5f * w1;
    float t1 = y1 - 0.5f * h1, b1 = y1 + 0.5f * h1;
    float l2 = x2 - 0.5f * w2, r2 = x2 + 0.5f * w2;
    float t2 = y2 - 0.5f * h2, b2 = y2 + 0.5f * h2;
    float in_h = fminf(b1, b2) - fmaxf(t1, t2);
    float in_w = fminf(r1, r2) - fmaxf(l1, l2);
    float inter = (in_h < 0.f || in_w < 0.f) ? 0.f : in_h * in_w;
    float a1 = (b1 - t1) * (r1 - l1);
    float a2 = (b2 - t2) * (r2 - l2);
    return inter / (a1 + a2 - inter);
}

// Compute the 5 loss terms for the cell at pp/lp, accumulate.
// Masked-out lanes return after reading only lp[0..1] (always-staged chunk).
__device__ __forceinline__ void cell_loss(const float* __restrict__ pp,
                                          const float* __restrict__ lp,
                                          float& v0, float& v1, float& v2,
                                          float& v3, float& v4) {
    const float2 l01 = *(const float2*)(lp);        // mask, gx
    const float mask = l01.x;
    if (mask == 0.f) return;

    const float2 l23 = *(const float2*)(lp + 2);    // gy, gw
    const float2 l45 = *(const float2*)(lp + 4);    // gh, -
    const float gx = l01.y, gy = l23.x, gw = l23.y, gh = l45.x;

    const float2 p01 = *(const float2*)(pp);        // -, b1x
    const float2 p23 = *(const float2*)(pp + 2);    // b1y, b1w
    const float2 p45 = *(const float2*)(pp + 4);    // b1h, -
    const float2 p67 = *(const float2*)(pp + 6);    // b2x, b2y
    const float2 p89 = *(const float2*)(pp + 8);    // b2w, b2h

    const float i1 = iou_f(p01.y, p23.x, p23.y, p45.x, gx, gy, gw, gh);
    const float i2 = iou_f(p67.x, p67.y, p89.x, p89.y, gx, gy, gw, gh);
    const bool best = (i1 >= i2);
    const float sx = best ? p01.y : p67.x;
    const float sy = best ? p23.x : p67.y;
    const float sw = best ? p23.y : p89.x;
    const float sh = best ? p45.x : p89.y;
    const float imax = best ? i1 : i2;
    const float imin = best ? i2 : i1;

    const float center = 5.f * ((sx - gx) * (sx - gx) + (sy - gy) * (sy - gy));
    const float dw = sqrtf(sw) - sqrtf(gw);
    const float dh = sqrtf(sh) - sqrtf(gh);
    const float wh = 5.f * (dw * dw + dh * dh);

    float cls = 0.f;
#pragma unroll
    for (int k = 0; k < 10; ++k) {                  // channels 10..29
        const float2 pd = *(const float2*)(pp + 10 + 2 * k);
        const float2 ld = *(const float2*)(lp + 10 + 2 * k);
        const float dx = pd.x - ld.x;
        const float dy = pd.y - ld.y;
        cls += dx * dx + dy * dy;
    }

    v0 += center * mask;
    v1 += wh * mask;
    v2 += imax * mask;
    v3 += imin * mask;
    v4 += cls * mask;
}

// Pipelined predicated staging:
//   - lab tiles double-buffered in LDS; tile t+NB staged while computing t.
//   - mask bits for tile t balloted ONE ITERATION AHEAD from the staged lab
//     tile (no serializing labels->ballot->pred chain inside an iteration).
//   - pred tile t staged PREDICATED per 16B chunk by those bits (~49% of pred
//     chunks skipped at p=0.3 mask density) -> ~147 MB total read vs 192.7.
//   All global loads of an iteration issue in one dependency-free burst.
__global__ __launch_bounds__(TPB) void yolo_partial(const float* __restrict__ pred,
                                                    const float* __restrict__ lab,
                                                    float* __restrict__ partial,
                                                    int n_cells) {
    __shared__ float sp[TW];                 // pred tile (7.68 KB)
    __shared__ float sl[2][TW];              // lab tiles cur/nxt (15.36 KB)
    __shared__ unsigned long long sbits;     // mask bits of the "current" tile
    __shared__ float red[5][TPB / 64];

    const int tid  = threadIdx.x;
    const int wave = tid >> 6;
    const int lane = tid & 63;
    const int bid  = blockIdx.x;
    const int NB   = gridDim.x;
    const int nt   = n_cells / TILE;         // 12544 full tiles

    // This thread's two float4-chunk indices within a 480-chunk array tile.
    const int  idx0 = tid;                   // always < 480
    const int  idx1 = TPB + tid;             // < 480 iff tid < 224
    const bool has1 = (idx1 < TF4);

    // Chunk -> covering-cell ids (compile-time divides by 30 -> magic mul).
    const int c00 = (4 * idx0) / NCH, c01 = (4 * idx0 + 3) / NCH;
    const int c10 = has1 ? (4 * idx1) / NCH : 0;
    const int c11 = has1 ? (4 * idx1 + 3) / NCH : 0;

    float v0 = 0.f, v1 = 0.f, v2 = 0.f, v3 = 0.f, v4 = 0.f;

    int cur = 0;
    unsigned long long bits = 0;

    if (bid < nt) {
        // ---- prologue: stage lab tile `bid` fully, ballot its masks ----
        {
            const size_t gbase = (size_t)bid * TW;
            float4 l0 = *(const float4*)(lab + gbase + (size_t)idx0 * 4);
            float4 l1;
            if (has1) l1 = *(const float4*)(lab + gbase + (size_t)idx1 * 4);
            *(float4*)(&sl[0][idx0 * 4]) = l0;
            if (has1) *(float4*)(&sl[0][idx1 * 4]) = l1;
        }
        __syncthreads();
        {
            const unsigned long long b =
                __ballot(tid < TILE && sl[0][tid * NCH] != 0.f);
            if (tid == 0) sbits = b;     // wave 0's ballot = the 64 cell bits
        }
        __syncthreads();
        bits = sbits;

        for (int t = bid; t < nt; t += NB) {
            const int  nxt = cur ^ 1;
            const bool have_next = (t + NB < nt);
            const size_t gbase = (size_t)t * TW;

            // ---- issue ALL loads for this iteration, dependency-free ----
            float4 p0, p1, l0, l1;
            const bool need0 = (((bits >> c00) & 1ull) | ((bits >> c01) & 1ull));
            const bool need1 = has1 &&
                               (((bits >> c10) & 1ull) | ((bits >> c11) & 1ull));
            if (need0) p0 = *(const float4*)(pred + gbase + (size_t)idx0 * 4);
            if (need1) p1 = *(const float4*)(pred + gbase + (size_t)idx1 * 4);
            if (have_next) {
                const size_t nbase = (size_t)(t + NB) * TW;
                l0 = *(const float4*)(lab + nbase + (size_t)idx0 * 4);
                if (has1) l1 = *(const float4*)(lab + nbase + (size_t)idx1 * 4);
            }

            // ---- spill to LDS (compiler inserts precise vmcnt waits) ----
            if (need0) *(float4*)(&sp[idx0 * 4]) = p0;
            if (need1) *(float4*)(&sp[idx1 * 4]) = p1;
            if (have_next) {
                *(float4*)(&sl[nxt][idx0 * 4]) = l0;
                if (has1) *(float4*)(&sl[nxt][idx1 * 4]) = l1;
            }
            __syncthreads();

            // ---- compute tile t (one cell per lane of wave 0) ----
            if (tid < TILE)
                cell_loss(sp + tid * NCH, &sl[cur][tid * NCH],
                          v0, v1, v2, v3, v4);

            // ---- ballot next tile's masks from the just-staged lab ----
            unsigned long long b = 0;
            if (have_next)
                b = __ballot(tid < TILE && sl[nxt][tid * NCH] != 0.f);
            if (tid == 0) sbits = b;
            __syncthreads();
            bits = sbits;
            cur = nxt;
        }
    }

    // Remainder cells — direct from global (never taken: 802816 % 64 == 0).
    const int rem_start = nt * TILE;
    if (bid == 0 && rem_start < n_cells) {
        for (int c = rem_start + tid; c < n_cells; c += TPB) {
            cell_loss(pred + (size_t)c * NCH, lab + (size_t)c * NCH,
                      v0, v1, v2, v3, v4);
        }
    }

    // ---- block reduction ----
#pragma unroll
    for (int off = 32; off > 0; off >>= 1) {
        v0 += __shfl_down(v0, off);
        v1 += __shfl_down(v1, off);
        v2 += __shfl_down(v2, off);
        v3 += __shfl_down(v3, off);
        v4 += __shfl_down(v4, off);
    }
    if (lane == 0) {
        red[0][wave] = v0;
        red[1][wave] = v1;
        red[2][wave] = v2;
        red[3][wave] = v3;
        red[4][wave] = v4;
    }
    __syncthreads();
    if (tid < 5) {
        float sacc = 0.f;
#pragma unroll
        for (int w = 0; w < TPB / 64; ++w) sacc += red[tid][w];
        partial[(size_t)bid * 5 + tid] = sacc;
    }
}

// Reduce n_blocks x 5 partials -> out[0..4]. One block.
__global__ __launch_bounds__(256) void final_reduce(const float* __restrict__ partial,
                                                    float* __restrict__ out,
                                                    int n_blocks) {
    __shared__ float red[5][4];
    const int tid = threadIdx.x;
    float v0 = 0.f, v1 = 0.f, v2 = 0.f, v3 = 0.f, v4 = 0.f;
    for (int b = tid; b < n_blocks; b += 256) {
        const float* p = partial + (size_t)b * 5;
        v0 += p[0]; v1 += p[1]; v2 += p[2]; v3 += p[3]; v4 += p[4];
    }
#pragma unroll
    for (int off = 32; off > 0; off >>= 1) {
        v0 += __shfl_down(v0, off);
        v1 += __shfl_down(v1, off);
        v2 += __shfl_down(v2, off);
        v3 += __shfl_down(v3, off);
        v4 += __shfl_down(v4, off);
    }
    const int wave = tid >> 6;
    const int lane = tid & 63;
    if (lane == 0) {
        red[0][wave] = v0;
        red[1][wave] = v1;
        red[2][wave] = v2;
        red[3][wave] = v3;
        red[4][wave] = v4;
    }
    __syncthreads();
    if (tid < 5) {
        float sacc = 0.f;
#pragma unroll
        for (int w = 0; w < 4; ++w) sacc += red[tid][w];
        out[tid] = sacc;
    }
}

extern "C" void kernel_launch(void* const* d_in, const int* in_sizes, int n_in,
                              void* d_out, int out_size, void* d_ws, size_t ws_size,
                              hipStream_t stream) {
    const float* pred = (const float*)d_in[0];
    const float* lab  = (const float*)d_in[1];
    float* out = (float*)d_out;
    float* partial = (float*)d_ws;                 // 1536*5*4 = 30,720 B

    const int n_cells = in_sizes[0] / NCH;         // 802816

    hipLaunchKernelGGL(yolo_partial, dim3(NBLK), dim3(TPB), 0, stream,
                       pred, lab, partial, n_cells);
    hipLaunchKernelGGL(final_reduce, dim3(1), dim3(256), 0, stream,
                       partial, out, NBLK);
}